// Round 12
// baseline (201.695 us; speedup 1.0000x reference)
//
#include <hip/hip_runtime.h>
#include <math.h>

#define NN 50000
#define NE 800000
#define NG 256
#define IND 128
#define NBUCK 98       // ceil(NN / 512)
#define CHUNK 4096
#define NPBLK ((NE + CHUNK - 1) / CHUNK)  // 196

typedef __bf16 bf16_t;
typedef bf16_t bf16x8 __attribute__((ext_vector_type(8)));
typedef float f32x4 __attribute__((ext_vector_type(4)));
typedef float floatx2 __attribute__((ext_vector_type(2)));
typedef unsigned short ushortx8 __attribute__((ext_vector_type(8)));

__device__ __forceinline__ float lrelu(float x) { return fmaxf(x, 0.2f * x); }
__device__ __forceinline__ float b2f(unsigned short u) {
  return __uint_as_float(((unsigned)u) << 16);
}
__device__ __forceinline__ float blo(unsigned u) { return __uint_as_float(u << 16); }
__device__ __forceinline__ float bhi(unsigned u) { return __uint_as_float(u & 0xffff0000u); }
__device__ __forceinline__ unsigned short f2b(float f) {
  unsigned u = __float_as_uint(f);
  return (unsigned short)((u + 0x7fffu + ((u >> 16) & 1u)) >> 16);
}
// static 4-way select (avoids runtime-indexed array -> scratch)
__device__ __forceinline__ float sel4(float v0, float v1, float v2, float v3, int g) {
  float a01 = (g & 1) ? v1 : v0;
  float a23 = (g & 1) ? v3 : v2;
  return (g & 2) ? a23 : a01;
}

// ---------------- zero counts (replaces slow runtime fill kernel) ----------------
__global__ __launch_bounds__(1024) void k_zero(int* __restrict__ counts) {
  int i = blockIdx.x * 1024 + threadIdx.x;
  if (i < NN) counts[i] = 0;
}

// ---------------- prep: W1 transpose + edge count (fused) ----------------
__global__ __launch_bounds__(256) void k_prep(const float* __restrict__ W1,
                                              const int* __restrict__ dst,
                                              unsigned short* __restrict__ w1t_hi,
                                              int* __restrict__ counts) {
  int tid = blockIdx.x * 256 + threadIdx.x;
  if (tid < 256 * IND) {
    int c = tid >> 7, k = tid & 127;  // output [c][k]
    w1t_hi[tid] = f2b(W1[(size_t)k * 256 + c]);
  }
  if (tid < NE) atomicAdd(&counts[dst[tid]], 1);
}

// ---------------- GEMM1 (MFMA, split-A in-register): feat1(fp8) = h @ W1 + el1/er1 ----------------
__global__ __launch_bounds__(256) void k_gemm1(const float* __restrict__ h,
                                               const unsigned short* __restrict__ w1t_hi,
                                               const float* __restrict__ al,
                                               const float* __restrict__ ar,
                                               unsigned int* __restrict__ feat1f8,  // [node][d] u32 = 4 fp8 (heads)
                                               float4* __restrict__ el1,
                                               float4* __restrict__ er1) {
  __shared__ unsigned short w1s[256 * IND];  // 64 KB, [col][k] swizzled
  int t = threadIdx.x;
  for (int i = t; i < 4096; i += 256) {  // 4096 ushort8 chunks
    int c = i >> 4, k8 = i & 15;
    ushortx8 v = ((const ushortx8*)w1t_hi)[i];
    int byte = (c * 256 + k8 * 16) ^ ((c & 7) << 4);
    *(ushortx8*)((char*)w1s + byte) = v;
  }
  __syncthreads();
  int w = t >> 6, l = t & 63;
  int c0 = l & 15, kg = l >> 4;
  int rw = blockIdx.x * 64 + w * 16;
  int arow = rw + c0;
  if (arow >= NN) arow = NN - 1;
  const float4* hp = (const float4*)h + (size_t)arow * 32 + kg * 2;
  f32x4 acc[16] = {};
#pragma unroll
  for (int ks = 0; ks < 4; ks++) {
    float4 v0 = hp[ks * 8], v1 = hp[ks * 8 + 1];
    float f[8] = {v0.x, v0.y, v0.z, v0.w, v1.x, v1.y, v1.z, v1.w};
    ushortx8 uh, ul;
#pragma unroll
    for (int j = 0; j < 8; j++) {
      unsigned short hj = f2b(f[j]);
      uh[j] = hj;
      ul[j] = f2b(f[j] - b2f(hj));
    }
    bf16x8 ah = *(bf16x8*)&uh;
    bf16x8 alo = *(bf16x8*)&ul;
#pragma unroll
    for (int n = 0; n < 16; n++) {
      int col = n * 16 + c0;
      int byte = (col * 256 + (ks * 4 + kg) * 16) ^ ((col & 7) << 4);
      bf16x8 b = *(const bf16x8*)(const void*)((const char*)w1s + byte);
      acc[n] = __builtin_amdgcn_mfma_f32_16x16x32_bf16(alo, b, acc[n], 0, 0, 0);
      acc[n] = __builtin_amdgcn_mfma_f32_16x16x32_bf16(ah, b, acc[n], 0, 0, 0);
    }
  }
  float alv[16], arv[16];
#pragma unroll
  for (int n = 0; n < 16; n++) {
    int ai = (n >> 2) * 64 + (n & 3) * 16 + c0;  // col ai = head*64 + d
    alv[n] = al[ai];
    arv[n] = ar[ai];
  }
#pragma unroll
  for (int j = 0; j < 4; j++) {
    int node = rw + kg * 4 + j;
    bool ok = node < NN;
    float pl[4] = {0.f, 0.f, 0.f, 0.f}, pr[4] = {0.f, 0.f, 0.f, 0.f};
    // pack fp8: for each dq, bytes hh=0..3 <- acc[(hh<<2)|dq][j]
#pragma unroll
    for (int dq = 0; dq < 4; dq++) {
      float v0 = acc[dq][j], v1 = acc[4 | dq][j], v2 = acc[8 | dq][j], v3 = acc[12 | dq][j];
      if (ok) {
        int u = __builtin_amdgcn_cvt_pk_fp8_f32(v0, v1, 0, false);
        u = __builtin_amdgcn_cvt_pk_fp8_f32(v2, v3, u, true);
        feat1f8[(size_t)node * 64 + dq * 16 + c0] = (unsigned)u;
      }
    }
#pragma unroll
    for (int n = 0; n < 16; n++) {
      float cv = acc[n][j];
      int hh = n >> 2;
      pl[hh] += cv * alv[n];
      pr[hh] += cv * arv[n];
    }
#pragma unroll
    for (int off = 1; off < 16; off <<= 1) {
#pragma unroll
      for (int hh = 0; hh < 4; hh++) {
        pl[hh] += __shfl_xor(pl[hh], off);
        pr[hh] += __shfl_xor(pr[hh], off);
      }
    }
    if (c0 == 0 && ok) {
      el1[node] = make_float4(pl[0], pl[1], pl[2], pl[3]);
      er1[node] = make_float4(pr[0], pr[1], pr[2], pr[3]);
    }
  }
}

// ---------------- hierarchical scan ----------------
#define NSB ((NN + 1023) / 1024)  // 49
__global__ __launch_bounds__(1024) void k_scanA(const int* __restrict__ counts,
                                                int* __restrict__ bsums) {
  int gid = blockIdx.x * 1024 + threadIdx.x;
  int v = (gid < NN) ? counts[gid] : 0;
#pragma unroll
  for (int off = 32; off; off >>= 1) v += __shfl_xor(v, off);
  __shared__ int ws[16];
  int w = threadIdx.x >> 6, l = threadIdx.x & 63;
  if (l == 0) ws[w] = v;
  __syncthreads();
  if (threadIdx.x == 0) {
    int s = 0;
#pragma unroll
    for (int i = 0; i < 16; i++) s += ws[i];
    bsums[blockIdx.x] = s;
  }
}

__global__ __launch_bounds__(64) void k_scanB(const int* __restrict__ bsums,
                                              int* __restrict__ boffs,
                                              int* __restrict__ bcursor) {
  int l = threadIdx.x;
  int orig = (l < NSB) ? bsums[l] : 0;
  int v = orig;
#pragma unroll
  for (int off = 1; off < 64; off <<= 1) {
    int tv = __shfl_up(v, off);
    if (l >= off) v += tv;
  }
  if (l < NSB) boffs[l] = v - orig;  // exclusive
  for (int i = l; i < NBUCK; i += 64) bcursor[i] = 0;
}

__global__ __launch_bounds__(1024) void k_scanC(const int* __restrict__ counts,
                                                const int* __restrict__ boffs,
                                                int* __restrict__ offs) {
  int gid = blockIdx.x * 1024 + threadIdx.x;
  int orig = (gid < NN) ? counts[gid] : 0;
  int v = orig;
  int w = threadIdx.x >> 6, l = threadIdx.x & 63;
#pragma unroll
  for (int off = 1; off < 64; off <<= 1) {
    int tv = __shfl_up(v, off);
    if (l >= off) v += tv;
  }
  __shared__ int ws[16];
  if (l == 63) ws[w] = v;
  __syncthreads();
  int woff = 0;
#pragma unroll
  for (int i = 0; i < 16; i++)
    if (i < w) woff += ws[i];
  if (gid < NN) offs[gid] = boffs[blockIdx.x] + woff + v - orig;
  if (gid == 0) offs[NN] = NE;
}

// ---------------- pass 1: partition edges into 98 dst-buckets (contiguous run writes) ----------------
__global__ __launch_bounds__(256) void k_part(const int* __restrict__ src, const int* __restrict__ dst,
                                              const int* __restrict__ offs, int* __restrict__ bcursor,
                                              int2* __restrict__ ebuf) {
  __shared__ int lcnt[NBUCK];
  __shared__ int lbase[NBUCK];
  __shared__ int gb[NBUCK];
  int t = threadIdx.x;
  for (int i = t; i < NBUCK; i += 256) lcnt[i] = 0;
  __syncthreads();
  int e0 = blockIdx.x * CHUNK;
  int sv[16], dv[16], rk[16];
#pragma unroll
  for (int i = 0; i < 16; i++) {
    int e = e0 + i * 256 + t;
    if (e < NE) {
      sv[i] = src[e];
      dv[i] = dst[e];
      rk[i] = atomicAdd(&lcnt[dv[i] >> 9], 1);
    }
  }
  __syncthreads();
  for (int i = t; i < NBUCK; i += 256) {
    lbase[i] = atomicAdd(&bcursor[i], lcnt[i]);
    gb[i] = offs[i << 9];
  }
  __syncthreads();
#pragma unroll
  for (int i = 0; i < 16; i++) {
    int e = e0 + i * 256 + t;
    if (e < NE) {
      int b = dv[i] >> 9;
      int2 v;
      v.x = sv[i];
      v.y = dv[i];
      ebuf[gb[b] + lbase[b] + rk[i]] = v;
    }
  }
}

// ---------------- pass 2: exact CSR placement within each bucket (LDS cursors, local writes) ----------------
__global__ __launch_bounds__(256) void k_scat2(const int2* __restrict__ ebuf, const int* __restrict__ offs,
                                               int2* __restrict__ sd) {
  __shared__ int lcur[512];
  int b = blockIdx.x, t = threadIdx.x;
  for (int i = t; i < 512; i += 256) lcur[i] = 0;
  int n0 = b << 9;
  int n1 = n0 + 512;
  if (n1 > NN) n1 = NN;
  int lo = offs[n0], hi = offs[n1];
  __syncthreads();
  for (int i = lo + t; i < hi; i += 256) {
    int2 p = ebuf[i];
    int pos = atomicAdd(&lcur[p.y - n0], 1);
    sd[offs[p.y] + pos] = p;
  }
}

// ---------------- edge records layer 1: {src, w0|w1, w2|w3, 0} ----------------
__global__ __launch_bounds__(256) void k_edge1(const int2* __restrict__ sd,
                                               const float4* __restrict__ el1,
                                               const float4* __restrict__ er1,
                                               int4* __restrict__ erec1) {
  int i = blockIdx.x * 256 + threadIdx.x;
  if (i >= NE) return;
  int2 p = sd[i];
  float4 l = el1[p.x], r = er1[p.y];
  unsigned w0 = f2b(__expf(lrelu(l.x + r.x)));
  unsigned w1 = f2b(__expf(lrelu(l.y + r.y)));
  unsigned w2 = f2b(__expf(lrelu(l.z + r.z)));
  unsigned w3 = f2b(__expf(lrelu(l.w + r.w)));
  int4 o;
  o.x = p.x;
  o.y = (int)(w0 | (w1 << 16));
  o.z = (int)(w2 | (w3 << 16));
  o.w = 0;
  erec1[i] = o;
}

// ---------------- aggregation layer 1: 4 edge-groups x 16 lanes, 8-wide main loop ----------------
// lane = g*16+q: group g handles edges i+g, i+4+g; lane covers dims 4q..4q+3 (all 4 heads).
__global__ __launch_bounds__(256) void k_agg1(const int* __restrict__ offs, const int4* __restrict__ erec1,
                                              const unsigned int* __restrict__ feat1f8,
                                              const float* __restrict__ b1,
                                              unsigned short* __restrict__ x1b) {
  int wid = (blockIdx.x * 256 + threadIdx.x) >> 6;
  int lane = threadIdx.x & 63;
  if (wid >= NN) return;
  int g = lane >> 4, q = lane & 15;
  int start = offs[wid], end = offs[wid + 1];
  float a[4][4] = {};  // [dj][head]
  float ds0 = 0.f, ds1 = 0.f, ds2 = 0.f, ds3 = 0.f;
  int i = start;
  for (; i + 8 <= end; i += 8) {
    int4 r0 = erec1[i + g];
    int4 r1 = erec1[i + 4 + g];
    uint4 u0 = *(const uint4*)(feat1f8 + (size_t)r0.x * 64 + q * 4);
    uint4 u1 = *(const uint4*)(feat1f8 + (size_t)r1.x * 64 + q * 4);
    float w00 = blo((unsigned)r0.y), w01 = bhi((unsigned)r0.y);
    float w02 = blo((unsigned)r0.z), w03 = bhi((unsigned)r0.z);
    float w10 = blo((unsigned)r1.y), w11 = bhi((unsigned)r1.y);
    float w12 = blo((unsigned)r1.z), w13 = bhi((unsigned)r1.z);
#pragma unroll
    for (int dj = 0; dj < 4; dj++) {
      unsigned ua = (&u0.x)[dj], ub = (&u1.x)[dj];
      floatx2 lo0 = __builtin_amdgcn_cvt_pk_f32_fp8(ua, false);
      floatx2 hi0 = __builtin_amdgcn_cvt_pk_f32_fp8(ua, true);
      floatx2 lo1 = __builtin_amdgcn_cvt_pk_f32_fp8(ub, false);
      floatx2 hi1 = __builtin_amdgcn_cvt_pk_f32_fp8(ub, true);
      a[dj][0] += w00 * lo0[0] + w10 * lo1[0];
      a[dj][1] += w01 * lo0[1] + w11 * lo1[1];
      a[dj][2] += w02 * hi0[0] + w12 * hi1[0];
      a[dj][3] += w03 * hi0[1] + w13 * hi1[1];
    }
    ds0 += w00 + w10; ds1 += w01 + w11; ds2 += w02 + w12; ds3 += w03 + w13;
  }
  for (; i < end; i += 4) {
    int e = i + g;
    bool valid = e < end;
    int ec = valid ? e : end - 1;
    int4 r0 = erec1[ec];
    float w00 = blo((unsigned)r0.y), w01 = bhi((unsigned)r0.y);
    float w02 = blo((unsigned)r0.z), w03 = bhi((unsigned)r0.z);
    if (!valid) { w00 = 0.f; w01 = 0.f; w02 = 0.f; w03 = 0.f; }
    uint4 u0 = *(const uint4*)(feat1f8 + (size_t)r0.x * 64 + q * 4);
#pragma unroll
    for (int dj = 0; dj < 4; dj++) {
      unsigned ua = (&u0.x)[dj];
      floatx2 lo0 = __builtin_amdgcn_cvt_pk_f32_fp8(ua, false);
      floatx2 hi0 = __builtin_amdgcn_cvt_pk_f32_fp8(ua, true);
      a[dj][0] += w00 * lo0[0];
      a[dj][1] += w01 * lo0[1];
      a[dj][2] += w02 * hi0[0];
      a[dj][3] += w03 * hi0[1];
    }
    ds0 += w00; ds1 += w01; ds2 += w02; ds3 += w03;
  }
  // combine the 4 edge-groups: butterfly over lane bits 4,5
#pragma unroll
  for (int off = 16; off < 64; off <<= 1) {
#pragma unroll
    for (int dj = 0; dj < 4; dj++) {
#pragma unroll
      for (int hh = 0; hh < 4; hh++) a[dj][hh] += __shfl_xor(a[dj][hh], off);
    }
    ds0 += __shfl_xor(ds0, off);
    ds1 += __shfl_xor(ds1, off);
    ds2 += __shfl_xor(ds2, off);
    ds3 += __shfl_xor(ds3, off);
  }
  // lane writes head g, dims 4q..4q+3
  float dsg = sel4(ds0, ds1, ds2, ds3, g);
  float inv = 1.f / fmaxf(dsg, 1e-9f);
  float4 bb = *(const float4*)(b1 + g * 64 + q * 4);
  ushort4 ov;
  ov.x = f2b(fmaxf(sel4(a[0][0], a[0][1], a[0][2], a[0][3], g) * inv + bb.x, 0.f));
  ov.y = f2b(fmaxf(sel4(a[1][0], a[1][1], a[1][2], a[1][3], g) * inv + bb.y, 0.f));
  ov.z = f2b(fmaxf(sel4(a[2][0], a[2][1], a[2][2], a[2][3], g) * inv + bb.z, 0.f));
  ov.w = f2b(fmaxf(sel4(a[3][0], a[3][1], a[3][2], a[3][3], g) * inv + bb.w, 0.f));
  *(ushort4*)(x1b + (size_t)wid * 256 + g * 64 + q * 4) = ov;
}

// ---------------- GEMM2 (MFMA bf16): feat2(fp8) = x1 @ W2 + el2/er2 ----------------
__global__ __launch_bounds__(256) void k_gemm2(const unsigned short* __restrict__ x1b,
                                               const float* __restrict__ W2,
                                               const float* __restrict__ al2,
                                               const float* __restrict__ ar2,
                                               unsigned int* __restrict__ feat2f8,  // [node][c0] u32 = 4 fp8 (cols c0,16+c0,32+c0,48+c0)
                                               float* __restrict__ el2,
                                               float* __restrict__ er2) {
  __shared__ unsigned short w2t[64 * 256];  // 32 KB, [col][k] swizzled
  int t = threadIdx.x;
  for (int i = t; i < 64 * 256; i += 256) {
    int k = i >> 6, col = i & 63;
    int kg = k >> 3;
    int s = (col * 32 + kg) ^ (col & 7);
    w2t[s * 8 + (k & 7)] = f2b(W2[i]);
  }
  __syncthreads();
  int w = t >> 6, l = t & 63;
  int rw = blockIdx.x * 64 + w * 16;
  int arow = rw + (l & 15);
  if (arow >= NN) arow = NN - 1;
  const unsigned short* aptr = x1b + (size_t)arow * 256 + (l >> 4) * 8;
  f32x4 acc[4] = {};
#pragma unroll
  for (int ks = 0; ks < 8; ks++) {
    bf16x8 a = *(const bf16x8*)(const void*)(aptr + ks * 32);
#pragma unroll
    for (int n = 0; n < 4; n++) {
      int colg = n * 16 + (l & 15);
      int kg = ks * 4 + (l >> 4);
      int s = (colg * 32 + kg) ^ (colg & 7);
      bf16x8 b = *(const bf16x8*)(const void*)&w2t[s * 8];
      acc[n] = __builtin_amdgcn_mfma_f32_16x16x32_bf16(a, b, acc[n], 0, 0, 0);
    }
  }
  float al2v[4], ar2v[4];
#pragma unroll
  for (int n = 0; n < 4; n++) { al2v[n] = al2[n * 16 + (l & 15)]; ar2v[n] = ar2[n * 16 + (l & 15)]; }
#pragma unroll
  for (int j = 0; j < 4; j++) {
    int node = rw + (l >> 4) * 4 + j;
    float pl = 0.f, pr = 0.f;
    float c0v = acc[0][j], c1v = acc[1][j], c2v = acc[2][j], c3v = acc[3][j];
    if (node < NN) {
      int u = __builtin_amdgcn_cvt_pk_fp8_f32(c0v, c1v, 0, false);
      u = __builtin_amdgcn_cvt_pk_fp8_f32(c2v, c3v, u, true);
      feat2f8[(size_t)node * 16 + (l & 15)] = (unsigned)u;
    }
    pl = c0v * al2v[0] + c1v * al2v[1] + c2v * al2v[2] + c3v * al2v[3];
    pr = c0v * ar2v[0] + c1v * ar2v[1] + c2v * ar2v[2] + c3v * ar2v[3];
#pragma unroll
    for (int off = 1; off < 16; off <<= 1) {
      pl += __shfl_xor(pl, off);
      pr += __shfl_xor(pr, off);
    }
    if ((l & 15) == 0 && node < NN) { el2[node] = pl; er2[node] = pr; }
  }
}

// ---------------- edge records layer 2: {src, w} ----------------
__global__ __launch_bounds__(256) void k_edge2(const int2* __restrict__ sd,
                                               const float* __restrict__ el2,
                                               const float* __restrict__ er2,
                                               int2* __restrict__ erec2) {
  int i = blockIdx.x * 256 + threadIdx.x;
  if (i >= NE) return;
  int2 p = sd[i];
  int2 o;
  o.x = p.x;
  o.y = __float_as_int(__expf(lrelu(el2[p.x] + er2[p.y])));
  erec2[i] = o;
}

// ---------------- aggregation layer 2: 4 edge-groups x 16 lanes, 8-wide; bf16 x2 out ----------------
__global__ __launch_bounds__(256) void k_agg2(const int* __restrict__ offs, const int2* __restrict__ erec2,
                                              const unsigned int* __restrict__ feat2f8,
                                              const float* __restrict__ b2,
                                              unsigned short* __restrict__ x2b) {
  int wid = (blockIdx.x * 256 + threadIdx.x) >> 6;
  int lane = threadIdx.x & 63;
  if (wid >= NN) return;
  int g = lane >> 4, q = lane & 15;
  int start = offs[wid], end = offs[wid + 1];
  float a0 = 0.f, a1 = 0.f, a2 = 0.f, a3 = 0.f, dsum = 0.f;
  int i = start;
  for (; i + 8 <= end; i += 8) {
    int2 r0 = erec2[i + g];
    int2 r1 = erec2[i + 4 + g];
    unsigned u0 = feat2f8[(size_t)r0.x * 16 + q];
    unsigned u1 = feat2f8[(size_t)r1.x * 16 + q];
    float w0 = __int_as_float(r0.y), w1 = __int_as_float(r1.y);
    floatx2 lo0 = __builtin_amdgcn_cvt_pk_f32_fp8(u0, false);
    floatx2 hi0 = __builtin_amdgcn_cvt_pk_f32_fp8(u0, true);
    floatx2 lo1 = __builtin_amdgcn_cvt_pk_f32_fp8(u1, false);
    floatx2 hi1 = __builtin_amdgcn_cvt_pk_f32_fp8(u1, true);
    a0 += w0 * lo0[0] + w1 * lo1[0];
    a1 += w0 * lo0[1] + w1 * lo1[1];
    a2 += w0 * hi0[0] + w1 * hi1[0];
    a3 += w0 * hi0[1] + w1 * hi1[1];
    dsum += w0 + w1;
  }
  for (; i < end; i += 4) {
    int e = i + g;
    bool valid = e < end;
    int ec = valid ? e : end - 1;
    int2 r0 = erec2[ec];
    float w0 = valid ? __int_as_float(r0.y) : 0.f;
    unsigned u0 = feat2f8[(size_t)r0.x * 16 + q];
    floatx2 lo0 = __builtin_amdgcn_cvt_pk_f32_fp8(u0, false);
    floatx2 hi0 = __builtin_amdgcn_cvt_pk_f32_fp8(u0, true);
    a0 += w0 * lo0[0];
    a1 += w0 * lo0[1];
    a2 += w0 * hi0[0];
    a3 += w0 * hi0[1];
    dsum += w0;
  }
#pragma unroll
  for (int off = 16; off < 64; off <<= 1) {
    a0 += __shfl_xor(a0, off);
    a1 += __shfl_xor(a1, off);
    a2 += __shfl_xor(a2, off);
    a3 += __shfl_xor(a3, off);
    dsum += __shfl_xor(dsum, off);
  }
  float inv = 1.f / fmaxf(dsum, 1e-9f);
  float av = sel4(a0, a1, a2, a3, g);  // dim g*16+q == lane
  x2b[(size_t)wid * 64 + lane] = f2b(fmaxf(av * inv + b2[lane], 0.f));
}

// ---------------- pooling + classifier head (deterministic, no atomics) ----------------
__global__ __launch_bounds__(1024) void k_pool(const unsigned short* __restrict__ x2b,
                                               const int* __restrict__ gid,
                                               const float* __restrict__ Wc,
                                               const float* __restrict__ bc,
                                               float* __restrict__ out) {
  int g = blockIdx.x;
  int t = threadIdx.x;
  int lo = 0, hi = NN;
  while (lo < hi) { int mid = (lo + hi) >> 1; if (gid[mid] < g) lo = mid + 1; else hi = mid; }
  int lb = lo;
  hi = NN;
  while (lo < hi) { int mid = (lo + hi) >> 1; if (gid[mid] < g + 1) lo = mid + 1; else hi = mid; }
  int le = lo;
  int d = t & 63, slice = t >> 6;  // 16 node-slices x 64 dims
  float s = 0.f;
  for (int n = lb + slice; n < le; n += 16) s += b2f(x2b[(size_t)n * 64 + d]);
  __shared__ float ws[16][64];
  ws[slice][d] = s;
  __syncthreads();
  if (t < 64) {
    float p = 0.f;
#pragma unroll
    for (int i = 0; i < 16; i++) p += ws[i][d];
    p /= fmaxf((float)(le - lb), 1.f);
    float a0 = p * Wc[d * 2 + 0];
    float a1 = p * Wc[d * 2 + 1];
#pragma unroll
    for (int off = 32; off; off >>= 1) { a0 += __shfl_xor(a0, off); a1 += __shfl_xor(a1, off); }
    if (d == 0) { out[g * 2 + 0] = a0 + bc[0]; out[g * 2 + 1] = a1 + bc[1]; }
  }
}

extern "C" void kernel_launch(void* const* d_in, const int* in_sizes, int n_in,
                              void* d_out, int out_size, void* d_ws, size_t ws_size,
                              hipStream_t stream) {
  const float* h = (const float*)d_in[0];
  const int* src = (const int*)d_in[1];
  const int* dst = (const int*)d_in[2];
  const int* gid = (const int*)d_in[3];
  const float* W1 = (const float*)d_in[4];
  const float* al1 = (const float*)d_in[5];
  const float* ar1 = (const float*)d_in[6];
  const float* b1 = (const float*)d_in[7];
  const float* W2 = (const float*)d_in[8];
  const float* al2 = (const float*)d_in[9];
  const float* ar2 = (const float*)d_in[10];
  const float* b2 = (const float*)d_in[11];
  const float* Wc = (const float*)d_in[12];
  const float* bc = (const float*)d_in[13];
  float* out = (float*)d_out;

  char* wsp = (char*)d_ws;
  size_t off = 0;
  auto take = [&](size_t bytes) -> void* {
    void* p = wsp + off;
    off = (off + bytes + 255) & ~(size_t)255;
    return p;
  };
  unsigned int* feat1f8 = (unsigned int*)take((size_t)NN * 256);          // 12.8 MB
  unsigned short* x1b = (unsigned short*)take((size_t)NN * 256 * 2);      // 25.6 MB
  unsigned int* feat2f8 = (unsigned int*)take((size_t)NN * 64);           // 3.2 MB
  unsigned short* x2b = (unsigned short*)take((size_t)NN * 64 * 2);       // 6.4 MB
  unsigned short* w1t_hi = (unsigned short*)take((size_t)256 * IND * 2);  // 64 KB
  float4* el1 = (float4*)take((size_t)NN * 16);
  float4* er1 = (float4*)take((size_t)NN * 16);
  float* el2 = (float*)take((size_t)NN * 4);
  float* er2 = (float*)take((size_t)NN * 4);
  int* counts = (int*)take((size_t)NN * 4);
  int* offs = (int*)take((size_t)(NN + 1) * 4);
  int2* sd = (int2*)take((size_t)NE * 8);            // 6.4 MB
  int2* ebuf = (int2*)take((size_t)NE * 8);          // 6.4 MB
  int4* erec1 = (int4*)take((size_t)NE * 16);        // 12.8 MB
  int2* erec2 = (int2*)take((size_t)NE * 8);         // 6.4 MB
  int* bsums = (int*)take((size_t)NSB * 4);
  int* boffs = (int*)take((size_t)NSB * 4);
  int* bcursor = (int*)take((size_t)NBUCK * 4);

  // zero counts with our own parallel kernel (runtime fill kernel was 40 us)
  k_zero<<<NSB, 1024, 0, stream>>>(counts);

  // prep (W1 transpose + edge count)
  k_prep<<<(NE + 255) / 256, 256, 0, stream>>>(W1, dst, w1t_hi, counts);

  // hierarchical scan + two-pass partition scatter
  k_scanA<<<NSB, 1024, 0, stream>>>(counts, bsums);
  k_scanB<<<1, 64, 0, stream>>>(bsums, boffs, bcursor);
  k_scanC<<<NSB, 1024, 0, stream>>>(counts, boffs, offs);
  k_part<<<NPBLK, 256, 0, stream>>>(src, dst, offs, bcursor, ebuf);
  k_scat2<<<NBUCK, 256, 0, stream>>>(ebuf, offs, sd);

  // layer 1
  k_gemm1<<<(NN + 63) / 64, 256, 0, stream>>>(h, w1t_hi, al1, ar1, feat1f8, el1, er1);
  k_edge1<<<(NE + 255) / 256, 256, 0, stream>>>(sd, el1, er1, erec1);
  k_agg1<<<(NN * 64 + 255) / 256, 256, 0, stream>>>(offs, erec1, feat1f8, b1, x1b);

  // layer 2
  k_gemm2<<<(NN + 63) / 64, 256, 0, stream>>>(x1b, W2, al2, ar2, feat2f8, el2, er2);
  k_edge2<<<(NE + 255) / 256, 256, 0, stream>>>(sd, el2, er2, erec2);
  k_agg2<<<(NN * 64 + 255) / 256, 256, 0, stream>>>(offs, erec2, feat2f8, b2, x2b);

  // pool + head (fused, atomic-free)
  k_pool<<<NG, 1024, 0, stream>>>(x2b, gid, Wc, bc, out);
}

// Round 13
// 196.676 us; speedup vs baseline: 1.0255x; 1.0255x over previous
//
#include <hip/hip_runtime.h>
#include <math.h>

#define NN 50000
#define NE 800000
#define NG 256
#define IND 128
#define NBUCK 98       // ceil(NN / 512)
#define CHUNK 4096
#define NPBLK ((NE + CHUNK - 1) / CHUNK)  // 196

typedef __bf16 bf16_t;
typedef bf16_t bf16x8 __attribute__((ext_vector_type(8)));
typedef float f32x4 __attribute__((ext_vector_type(4)));
typedef float floatx2 __attribute__((ext_vector_type(2)));
typedef unsigned short ushortx8 __attribute__((ext_vector_type(8)));

__device__ __forceinline__ float lrelu(float x) { return fmaxf(x, 0.2f * x); }
__device__ __forceinline__ float b2f(unsigned short u) {
  return __uint_as_float(((unsigned)u) << 16);
}
__device__ __forceinline__ float blo(unsigned u) { return __uint_as_float(u << 16); }
__device__ __forceinline__ float bhi(unsigned u) { return __uint_as_float(u & 0xffff0000u); }
__device__ __forceinline__ unsigned short f2b(float f) {
  unsigned u = __float_as_uint(f);
  return (unsigned short)((u + 0x7fffu + ((u >> 16) & 1u)) >> 16);
}
// static 4-way select (avoids runtime-indexed array -> scratch)
__device__ __forceinline__ float sel4(float v0, float v1, float v2, float v3, int g) {
  float a01 = (g & 1) ? v1 : v0;
  float a23 = (g & 1) ? v3 : v2;
  return (g & 2) ? a23 : a01;
}

// ---------------- zero counts ----------------
__global__ __launch_bounds__(1024) void k_zero(int* __restrict__ counts) {
  int i = blockIdx.x * 1024 + threadIdx.x;
  if (i < NN) counts[i] = 0;
}

// ---------------- prep: W1 transpose + W2 swizzle + edge count (fused) ----------------
__global__ __launch_bounds__(256) void k_prep(const float* __restrict__ W1,
                                              const float* __restrict__ W2,
                                              const int* __restrict__ dst,
                                              unsigned short* __restrict__ w1t_hi,
                                              unsigned short* __restrict__ w2t_pre,
                                              int* __restrict__ counts) {
  int tid = blockIdx.x * 256 + threadIdx.x;
  if (tid < 256 * IND) {
    int c = tid >> 7, k = tid & 127;  // output [c][k]
    w1t_hi[tid] = f2b(W1[(size_t)k * 256 + c]);
  } else if (tid < 256 * IND + 64 * 256) {
    int idx = tid - 256 * IND;  // idx = k*64+col
    int k = idx >> 6, col = idx & 63;
    int kg = k >> 3;
    int s = (col * 32 + kg) ^ (col & 7);
    w2t_pre[s * 8 + (k & 7)] = f2b(W2[idx]);
  }
  if (tid < NE) atomicAdd(&counts[dst[tid]], 1);
}

// ---------------- GEMM1 (MFMA, split-A in-register): feat1(fp8) = h @ W1 + el1/er1 ----------------
__global__ __launch_bounds__(256) void k_gemm1(const float* __restrict__ h,
                                               const unsigned short* __restrict__ w1t_hi,
                                               const float* __restrict__ al,
                                               const float* __restrict__ ar,
                                               unsigned int* __restrict__ feat1f8,  // [node][d] u32 = 4 fp8 (heads)
                                               float4* __restrict__ el1,
                                               float4* __restrict__ er1) {
  __shared__ unsigned short w1s[256 * IND];  // 64 KB, [col][k] swizzled
  int t = threadIdx.x;
  for (int i = t; i < 4096; i += 256) {  // 4096 ushort8 chunks
    int c = i >> 4, k8 = i & 15;
    ushortx8 v = ((const ushortx8*)w1t_hi)[i];
    int byte = (c * 256 + k8 * 16) ^ ((c & 7) << 4);
    *(ushortx8*)((char*)w1s + byte) = v;
  }
  __syncthreads();
  int w = t >> 6, l = t & 63;
  int c0 = l & 15, kg = l >> 4;
  int rw = blockIdx.x * 64 + w * 16;
  int arow = rw + c0;
  if (arow >= NN) arow = NN - 1;
  const float4* hp = (const float4*)h + (size_t)arow * 32 + kg * 2;
  f32x4 acc[16] = {};
#pragma unroll
  for (int ks = 0; ks < 4; ks++) {
    float4 v0 = hp[ks * 8], v1 = hp[ks * 8 + 1];
    float f[8] = {v0.x, v0.y, v0.z, v0.w, v1.x, v1.y, v1.z, v1.w};
    ushortx8 uh, ul;
#pragma unroll
    for (int j = 0; j < 8; j++) {
      unsigned short hj = f2b(f[j]);
      uh[j] = hj;
      ul[j] = f2b(f[j] - b2f(hj));
    }
    bf16x8 ah = *(bf16x8*)&uh;
    bf16x8 alo = *(bf16x8*)&ul;
#pragma unroll
    for (int n = 0; n < 16; n++) {
      int col = n * 16 + c0;
      int byte = (col * 256 + (ks * 4 + kg) * 16) ^ ((col & 7) << 4);
      bf16x8 b = *(const bf16x8*)(const void*)((const char*)w1s + byte);
      acc[n] = __builtin_amdgcn_mfma_f32_16x16x32_bf16(alo, b, acc[n], 0, 0, 0);
      acc[n] = __builtin_amdgcn_mfma_f32_16x16x32_bf16(ah, b, acc[n], 0, 0, 0);
    }
  }
  float alv[16], arv[16];
#pragma unroll
  for (int n = 0; n < 16; n++) {
    int ai = (n >> 2) * 64 + (n & 3) * 16 + c0;  // col ai = head*64 + d
    alv[n] = al[ai];
    arv[n] = ar[ai];
  }
#pragma unroll
  for (int j = 0; j < 4; j++) {
    int node = rw + kg * 4 + j;
    bool ok = node < NN;
    float pl[4] = {0.f, 0.f, 0.f, 0.f}, pr[4] = {0.f, 0.f, 0.f, 0.f};
    // pack fp8: for each dq, bytes hh=0..3 <- acc[(hh<<2)|dq][j]
#pragma unroll
    for (int dq = 0; dq < 4; dq++) {
      float v0 = acc[dq][j], v1 = acc[4 | dq][j], v2 = acc[8 | dq][j], v3 = acc[12 | dq][j];
      if (ok) {
        int u = __builtin_amdgcn_cvt_pk_fp8_f32(v0, v1, 0, false);
        u = __builtin_amdgcn_cvt_pk_fp8_f32(v2, v3, u, true);
        feat1f8[(size_t)node * 64 + dq * 16 + c0] = (unsigned)u;
      }
    }
#pragma unroll
    for (int n = 0; n < 16; n++) {
      float cv = acc[n][j];
      int hh = n >> 2;
      pl[hh] += cv * alv[n];
      pr[hh] += cv * arv[n];
    }
#pragma unroll
    for (int off = 1; off < 16; off <<= 1) {
#pragma unroll
      for (int hh = 0; hh < 4; hh++) {
        pl[hh] += __shfl_xor(pl[hh], off);
        pr[hh] += __shfl_xor(pr[hh], off);
      }
    }
    if (c0 == 0 && ok) {
      el1[node] = make_float4(pl[0], pl[1], pl[2], pl[3]);
      er1[node] = make_float4(pr[0], pr[1], pr[2], pr[3]);
    }
  }
}

// ---------------- hierarchical scan ----------------
#define NSB ((NN + 1023) / 1024)  // 49
__global__ __launch_bounds__(1024) void k_scanA(const int* __restrict__ counts,
                                                int* __restrict__ bsums) {
  int gid = blockIdx.x * 1024 + threadIdx.x;
  int v = (gid < NN) ? counts[gid] : 0;
#pragma unroll
  for (int off = 32; off; off >>= 1) v += __shfl_xor(v, off);
  __shared__ int ws[16];
  int w = threadIdx.x >> 6, l = threadIdx.x & 63;
  if (l == 0) ws[w] = v;
  __syncthreads();
  if (threadIdx.x == 0) {
    int s = 0;
#pragma unroll
    for (int i = 0; i < 16; i++) s += ws[i];
    bsums[blockIdx.x] = s;
  }
}

__global__ __launch_bounds__(64) void k_scanB(const int* __restrict__ bsums,
                                              int* __restrict__ boffs,
                                              int* __restrict__ bcursor) {
  int l = threadIdx.x;
  int orig = (l < NSB) ? bsums[l] : 0;
  int v = orig;
#pragma unroll
  for (int off = 1; off < 64; off <<= 1) {
    int tv = __shfl_up(v, off);
    if (l >= off) v += tv;
  }
  if (l < NSB) boffs[l] = v - orig;  // exclusive
  for (int i = l; i < NBUCK; i += 64) bcursor[i] = 0;
}

__global__ __launch_bounds__(1024) void k_scanC(const int* __restrict__ counts,
                                                const int* __restrict__ boffs,
                                                int* __restrict__ offs) {
  int gid = blockIdx.x * 1024 + threadIdx.x;
  int orig = (gid < NN) ? counts[gid] : 0;
  int v = orig;
  int w = threadIdx.x >> 6, l = threadIdx.x & 63;
#pragma unroll
  for (int off = 1; off < 64; off <<= 1) {
    int tv = __shfl_up(v, off);
    if (l >= off) v += tv;
  }
  __shared__ int ws[16];
  if (l == 63) ws[w] = v;
  __syncthreads();
  int woff = 0;
#pragma unroll
  for (int i = 0; i < 16; i++)
    if (i < w) woff += ws[i];
  if (gid < NN) offs[gid] = boffs[blockIdx.x] + woff + v - orig;
  if (gid == 0) offs[NN] = NE;
}

// ---------------- pass 1: partition edges into 98 dst-buckets ----------------
__global__ __launch_bounds__(256) void k_part(const int* __restrict__ src, const int* __restrict__ dst,
                                              const int* __restrict__ offs, int* __restrict__ bcursor,
                                              int2* __restrict__ ebuf) {
  __shared__ int lcnt[NBUCK];
  __shared__ int lbase[NBUCK];
  __shared__ int gb[NBUCK];
  int t = threadIdx.x;
  for (int i = t; i < NBUCK; i += 256) lcnt[i] = 0;
  __syncthreads();
  int e0 = blockIdx.x * CHUNK;
  int sv[16], dv[16], rk[16];
#pragma unroll
  for (int i = 0; i < 16; i++) {
    int e = e0 + i * 256 + t;
    if (e < NE) {
      sv[i] = src[e];
      dv[i] = dst[e];
      rk[i] = atomicAdd(&lcnt[dv[i] >> 9], 1);
    }
  }
  __syncthreads();
  for (int i = t; i < NBUCK; i += 256) {
    lbase[i] = atomicAdd(&bcursor[i], lcnt[i]);
    gb[i] = offs[i << 9];
  }
  __syncthreads();
#pragma unroll
  for (int i = 0; i < 16; i++) {
    int e = e0 + i * 256 + t;
    if (e < NE) {
      int b = dv[i] >> 9;
      int2 v;
      v.x = sv[i];
      v.y = dv[i];
      ebuf[gb[b] + lbase[b] + rk[i]] = v;
    }
  }
}

// ---------------- pass 2: exact CSR placement within each bucket ----------------
__global__ __launch_bounds__(256) void k_scat2(const int2* __restrict__ ebuf, const int* __restrict__ offs,
                                               int2* __restrict__ sd) {
  __shared__ int lcur[512];
  int b = blockIdx.x, t = threadIdx.x;
  for (int i = t; i < 512; i += 256) lcur[i] = 0;
  int n0 = b << 9;
  int n1 = n0 + 512;
  if (n1 > NN) n1 = NN;
  int lo = offs[n0], hi = offs[n1];
  __syncthreads();
  for (int i = lo + t; i < hi; i += 256) {
    int2 p = ebuf[i];
    int pos = atomicAdd(&lcur[p.y - n0], 1);
    sd[offs[p.y] + pos] = p;
  }
}

// ---------------- edge records layer 1: {src, w0|w1, w2|w3, 0} ----------------
__global__ __launch_bounds__(256) void k_edge1(const int2* __restrict__ sd,
                                               const float4* __restrict__ el1,
                                               const float4* __restrict__ er1,
                                               int4* __restrict__ erec1) {
  int i = blockIdx.x * 256 + threadIdx.x;
  if (i >= NE) return;
  int2 p = sd[i];
  float4 l = el1[p.x], r = er1[p.y];
  unsigned w0 = f2b(__expf(lrelu(l.x + r.x)));
  unsigned w1 = f2b(__expf(lrelu(l.y + r.y)));
  unsigned w2 = f2b(__expf(lrelu(l.z + r.z)));
  unsigned w3 = f2b(__expf(lrelu(l.w + r.w)));
  int4 o;
  o.x = p.x;
  o.y = (int)(w0 | (w1 << 16));
  o.z = (int)(w2 | (w3 << 16));
  o.w = 0;
  erec1[i] = o;
}

// ---------------- aggregation layer 1: 4 edge-groups x 16 lanes, 16-wide main loop ----------------
__global__ __launch_bounds__(256) void k_agg1(const int* __restrict__ offs, const int4* __restrict__ erec1,
                                              const unsigned int* __restrict__ feat1f8,
                                              const float* __restrict__ b1,
                                              unsigned short* __restrict__ x1b) {
  int wid = (blockIdx.x * 256 + threadIdx.x) >> 6;
  int lane = threadIdx.x & 63;
  if (wid >= NN) return;
  int g = lane >> 4, q = lane & 15;
  int start = offs[wid], end = offs[wid + 1];
  float a[4][4] = {};  // [dj][head]
  float ds0 = 0.f, ds1 = 0.f, ds2 = 0.f, ds3 = 0.f;
  int i = start;
  for (; i + 16 <= end; i += 16) {
    int4 r0 = erec1[i + g];
    int4 r1 = erec1[i + 4 + g];
    int4 r2 = erec1[i + 8 + g];
    int4 r3 = erec1[i + 12 + g];
    uint4 u0 = *(const uint4*)(feat1f8 + (size_t)r0.x * 64 + q * 4);
    uint4 u1 = *(const uint4*)(feat1f8 + (size_t)r1.x * 64 + q * 4);
    uint4 u2 = *(const uint4*)(feat1f8 + (size_t)r2.x * 64 + q * 4);
    uint4 u3 = *(const uint4*)(feat1f8 + (size_t)r3.x * 64 + q * 4);
    float w00 = blo((unsigned)r0.y), w01 = bhi((unsigned)r0.y);
    float w02 = blo((unsigned)r0.z), w03 = bhi((unsigned)r0.z);
    float w10 = blo((unsigned)r1.y), w11 = bhi((unsigned)r1.y);
    float w12 = blo((unsigned)r1.z), w13 = bhi((unsigned)r1.z);
    float w20 = blo((unsigned)r2.y), w21 = bhi((unsigned)r2.y);
    float w22 = blo((unsigned)r2.z), w23 = bhi((unsigned)r2.z);
    float w30 = blo((unsigned)r3.y), w31 = bhi((unsigned)r3.y);
    float w32 = blo((unsigned)r3.z), w33 = bhi((unsigned)r3.z);
#pragma unroll
    for (int dj = 0; dj < 4; dj++) {
      unsigned ua = (&u0.x)[dj], ub = (&u1.x)[dj], uc = (&u2.x)[dj], ud = (&u3.x)[dj];
      floatx2 loa = __builtin_amdgcn_cvt_pk_f32_fp8(ua, false);
      floatx2 hia = __builtin_amdgcn_cvt_pk_f32_fp8(ua, true);
      floatx2 lob = __builtin_amdgcn_cvt_pk_f32_fp8(ub, false);
      floatx2 hib = __builtin_amdgcn_cvt_pk_f32_fp8(ub, true);
      floatx2 loc = __builtin_amdgcn_cvt_pk_f32_fp8(uc, false);
      floatx2 hic = __builtin_amdgcn_cvt_pk_f32_fp8(uc, true);
      floatx2 lod = __builtin_amdgcn_cvt_pk_f32_fp8(ud, false);
      floatx2 hid = __builtin_amdgcn_cvt_pk_f32_fp8(ud, true);
      a[dj][0] += w00 * loa[0] + w10 * lob[0] + w20 * loc[0] + w30 * lod[0];
      a[dj][1] += w01 * loa[1] + w11 * lob[1] + w21 * loc[1] + w31 * lod[1];
      a[dj][2] += w02 * hia[0] + w12 * hib[0] + w22 * hic[0] + w32 * hid[0];
      a[dj][3] += w03 * hia[1] + w13 * hib[1] + w23 * hic[1] + w33 * hid[1];
    }
    ds0 += w00 + w10 + w20 + w30;
    ds1 += w01 + w11 + w21 + w31;
    ds2 += w02 + w12 + w22 + w32;
    ds3 += w03 + w13 + w23 + w33;
  }
  for (; i + 8 <= end; i += 8) {
    int4 r0 = erec1[i + g];
    int4 r1 = erec1[i + 4 + g];
    uint4 u0 = *(const uint4*)(feat1f8 + (size_t)r0.x * 64 + q * 4);
    uint4 u1 = *(const uint4*)(feat1f8 + (size_t)r1.x * 64 + q * 4);
    float w00 = blo((unsigned)r0.y), w01 = bhi((unsigned)r0.y);
    float w02 = blo((unsigned)r0.z), w03 = bhi((unsigned)r0.z);
    float w10 = blo((unsigned)r1.y), w11 = bhi((unsigned)r1.y);
    float w12 = blo((unsigned)r1.z), w13 = bhi((unsigned)r1.z);
#pragma unroll
    for (int dj = 0; dj < 4; dj++) {
      unsigned ua = (&u0.x)[dj], ub = (&u1.x)[dj];
      floatx2 lo0 = __builtin_amdgcn_cvt_pk_f32_fp8(ua, false);
      floatx2 hi0 = __builtin_amdgcn_cvt_pk_f32_fp8(ua, true);
      floatx2 lo1 = __builtin_amdgcn_cvt_pk_f32_fp8(ub, false);
      floatx2 hi1 = __builtin_amdgcn_cvt_pk_f32_fp8(ub, true);
      a[dj][0] += w00 * lo0[0] + w10 * lo1[0];
      a[dj][1] += w01 * lo0[1] + w11 * lo1[1];
      a[dj][2] += w02 * hi0[0] + w12 * hi1[0];
      a[dj][3] += w03 * hi0[1] + w13 * hi1[1];
    }
    ds0 += w00 + w10; ds1 += w01 + w11; ds2 += w02 + w12; ds3 += w03 + w13;
  }
  for (; i < end; i += 4) {
    int e = i + g;
    bool valid = e < end;
    int ec = valid ? e : end - 1;
    int4 r0 = erec1[ec];
    float w00 = blo((unsigned)r0.y), w01 = bhi((unsigned)r0.y);
    float w02 = blo((unsigned)r0.z), w03 = bhi((unsigned)r0.z);
    if (!valid) { w00 = 0.f; w01 = 0.f; w02 = 0.f; w03 = 0.f; }
    uint4 u0 = *(const uint4*)(feat1f8 + (size_t)r0.x * 64 + q * 4);
#pragma unroll
    for (int dj = 0; dj < 4; dj++) {
      unsigned ua = (&u0.x)[dj];
      floatx2 lo0 = __builtin_amdgcn_cvt_pk_f32_fp8(ua, false);
      floatx2 hi0 = __builtin_amdgcn_cvt_pk_f32_fp8(ua, true);
      a[dj][0] += w00 * lo0[0];
      a[dj][1] += w01 * lo0[1];
      a[dj][2] += w02 * hi0[0];
      a[dj][3] += w03 * hi0[1];
    }
    ds0 += w00; ds1 += w01; ds2 += w02; ds3 += w03;
  }
  // combine the 4 edge-groups: butterfly over lane bits 4,5
#pragma unroll
  for (int off = 16; off < 64; off <<= 1) {
#pragma unroll
    for (int dj = 0; dj < 4; dj++) {
#pragma unroll
      for (int hh = 0; hh < 4; hh++) a[dj][hh] += __shfl_xor(a[dj][hh], off);
    }
    ds0 += __shfl_xor(ds0, off);
    ds1 += __shfl_xor(ds1, off);
    ds2 += __shfl_xor(ds2, off);
    ds3 += __shfl_xor(ds3, off);
  }
  // lane writes head g, dims 4q..4q+3
  float dsg = sel4(ds0, ds1, ds2, ds3, g);
  float inv = 1.f / fmaxf(dsg, 1e-9f);
  float4 bb = *(const float4*)(b1 + g * 64 + q * 4);
  ushort4 ov;
  ov.x = f2b(fmaxf(sel4(a[0][0], a[0][1], a[0][2], a[0][3], g) * inv + bb.x, 0.f));
  ov.y = f2b(fmaxf(sel4(a[1][0], a[1][1], a[1][2], a[1][3], g) * inv + bb.y, 0.f));
  ov.z = f2b(fmaxf(sel4(a[2][0], a[2][1], a[2][2], a[2][3], g) * inv + bb.z, 0.f));
  ov.w = f2b(fmaxf(sel4(a[3][0], a[3][1], a[3][2], a[3][3], g) * inv + bb.w, 0.f));
  *(ushort4*)(x1b + (size_t)wid * 256 + g * 64 + q * 4) = ov;
}

// ---------------- GEMM2 (MFMA bf16): feat2(fp8) = x1 @ W2 + el2/er2 ----------------
__global__ __launch_bounds__(256) void k_gemm2(const unsigned short* __restrict__ x1b,
                                               const unsigned short* __restrict__ w2t_pre,
                                               const float* __restrict__ al2,
                                               const float* __restrict__ ar2,
                                               unsigned int* __restrict__ feat2f8,
                                               float* __restrict__ el2,
                                               float* __restrict__ er2) {
  __shared__ unsigned short w2t[64 * 256];  // 32 KB, pre-swizzled
  int t = threadIdx.x;
  for (int i = t; i < 2048; i += 256)
    ((ushortx8*)w2t)[i] = ((const ushortx8*)w2t_pre)[i];
  __syncthreads();
  int w = t >> 6, l = t & 63;
  int rw = blockIdx.x * 64 + w * 16;
  int arow = rw + (l & 15);
  if (arow >= NN) arow = NN - 1;
  const unsigned short* aptr = x1b + (size_t)arow * 256 + (l >> 4) * 8;
  f32x4 acc[4] = {};
#pragma unroll
  for (int ks = 0; ks < 8; ks++) {
    bf16x8 a = *(const bf16x8*)(const void*)(aptr + ks * 32);
#pragma unroll
    for (int n = 0; n < 4; n++) {
      int colg = n * 16 + (l & 15);
      int kg = ks * 4 + (l >> 4);
      int s = (colg * 32 + kg) ^ (colg & 7);
      bf16x8 b = *(const bf16x8*)(const void*)&w2t[s * 8];
      acc[n] = __builtin_amdgcn_mfma_f32_16x16x32_bf16(a, b, acc[n], 0, 0, 0);
    }
  }
  float al2v[4], ar2v[4];
#pragma unroll
  for (int n = 0; n < 4; n++) { al2v[n] = al2[n * 16 + (l & 15)]; ar2v[n] = ar2[n * 16 + (l & 15)]; }
#pragma unroll
  for (int j = 0; j < 4; j++) {
    int node = rw + (l >> 4) * 4 + j;
    float pl = 0.f, pr = 0.f;
    float c0v = acc[0][j], c1v = acc[1][j], c2v = acc[2][j], c3v = acc[3][j];
    if (node < NN) {
      int u = __builtin_amdgcn_cvt_pk_fp8_f32(c0v, c1v, 0, false);
      u = __builtin_amdgcn_cvt_pk_fp8_f32(c2v, c3v, u, true);
      feat2f8[(size_t)node * 16 + (l & 15)] = (unsigned)u;
    }
    pl = c0v * al2v[0] + c1v * al2v[1] + c2v * al2v[2] + c3v * al2v[3];
    pr = c0v * ar2v[0] + c1v * ar2v[1] + c2v * ar2v[2] + c3v * ar2v[3];
#pragma unroll
    for (int off = 1; off < 16; off <<= 1) {
      pl += __shfl_xor(pl, off);
      pr += __shfl_xor(pr, off);
    }
    if ((l & 15) == 0 && node < NN) { el2[node] = pl; er2[node] = pr; }
  }
}

// ---------------- aggregation layer 2 (fused edge weights): 4 groups x 16 lanes, 16-wide ----------------
__global__ __launch_bounds__(256) void k_agg2(const int* __restrict__ offs, const int2* __restrict__ sd,
                                              const float* __restrict__ el2, const float* __restrict__ er2,
                                              const unsigned int* __restrict__ feat2f8,
                                              const float* __restrict__ b2,
                                              unsigned short* __restrict__ x2b) {
  int wid = (blockIdx.x * 256 + threadIdx.x) >> 6;
  int lane = threadIdx.x & 63;
  if (wid >= NN) return;
  int g = lane >> 4, q = lane & 15;
  int start = offs[wid], end = offs[wid + 1];
  float erv = er2[wid];
  float a0 = 0.f, a1 = 0.f, a2 = 0.f, a3 = 0.f, dsum = 0.f;
  int i = start;
  for (; i + 16 <= end; i += 16) {
    int2 p0 = sd[i + g], p1 = sd[i + 4 + g], p2 = sd[i + 8 + g], p3 = sd[i + 12 + g];
    unsigned u0 = feat2f8[(size_t)p0.x * 16 + q];
    unsigned u1 = feat2f8[(size_t)p1.x * 16 + q];
    unsigned u2 = feat2f8[(size_t)p2.x * 16 + q];
    unsigned u3 = feat2f8[(size_t)p3.x * 16 + q];
    float w0 = __expf(lrelu(el2[p0.x] + erv));
    float w1 = __expf(lrelu(el2[p1.x] + erv));
    float w2 = __expf(lrelu(el2[p2.x] + erv));
    float w3 = __expf(lrelu(el2[p3.x] + erv));
    floatx2 lo0 = __builtin_amdgcn_cvt_pk_f32_fp8(u0, false);
    floatx2 hi0 = __builtin_amdgcn_cvt_pk_f32_fp8(u0, true);
    floatx2 lo1 = __builtin_amdgcn_cvt_pk_f32_fp8(u1, false);
    floatx2 hi1 = __builtin_amdgcn_cvt_pk_f32_fp8(u1, true);
    floatx2 lo2 = __builtin_amdgcn_cvt_pk_f32_fp8(u2, false);
    floatx2 hi2 = __builtin_amdgcn_cvt_pk_f32_fp8(u2, true);
    floatx2 lo3 = __builtin_amdgcn_cvt_pk_f32_fp8(u3, false);
    floatx2 hi3 = __builtin_amdgcn_cvt_pk_f32_fp8(u3, true);
    a0 += w0 * lo0[0] + w1 * lo1[0] + w2 * lo2[0] + w3 * lo3[0];
    a1 += w0 * lo0[1] + w1 * lo1[1] + w2 * lo2[1] + w3 * lo3[1];
    a2 += w0 * hi0[0] + w1 * hi1[0] + w2 * hi2[0] + w3 * hi3[0];
    a3 += w0 * hi0[1] + w1 * hi1[1] + w2 * hi2[1] + w3 * hi3[1];
    dsum += w0 + w1 + w2 + w3;
  }
  for (; i + 8 <= end; i += 8) {
    int2 p0 = sd[i + g], p1 = sd[i + 4 + g];
    unsigned u0 = feat2f8[(size_t)p0.x * 16 + q];
    unsigned u1 = feat2f8[(size_t)p1.x * 16 + q];
    float w0 = __expf(lrelu(el2[p0.x] + erv));
    float w1 = __expf(lrelu(el2[p1.x] + erv));
    floatx2 lo0 = __builtin_amdgcn_cvt_pk_f32_fp8(u0, false);
    floatx2 hi0 = __builtin_amdgcn_cvt_pk_f32_fp8(u0, true);
    floatx2 lo1 = __builtin_amdgcn_cvt_pk_f32_fp8(u1, false);
    floatx2 hi1 = __builtin_amdgcn_cvt_pk_f32_fp8(u1, true);
    a0 += w0 * lo0[0] + w1 * lo1[0];
    a1 += w0 * lo0[1] + w1 * lo1[1];
    a2 += w0 * hi0[0] + w1 * hi1[0];
    a3 += w0 * hi0[1] + w1 * hi1[1];
    dsum += w0 + w1;
  }
  for (; i < end; i += 4) {
    int e = i + g;
    bool valid = e < end;
    int ec = valid ? e : end - 1;
    int2 p0 = sd[ec];
    float w0 = __expf(lrelu(el2[p0.x] + erv));
    if (!valid) w0 = 0.f;
    unsigned u0 = feat2f8[(size_t)p0.x * 16 + q];
    floatx2 lo0 = __builtin_amdgcn_cvt_pk_f32_fp8(u0, false);
    floatx2 hi0 = __builtin_amdgcn_cvt_pk_f32_fp8(u0, true);
    a0 += w0 * lo0[0];
    a1 += w0 * lo0[1];
    a2 += w0 * hi0[0];
    a3 += w0 * hi0[1];
    dsum += w0;
  }
#pragma unroll
  for (int off = 16; off < 64; off <<= 1) {
    a0 += __shfl_xor(a0, off);
    a1 += __shfl_xor(a1, off);
    a2 += __shfl_xor(a2, off);
    a3 += __shfl_xor(a3, off);
    dsum += __shfl_xor(dsum, off);
  }
  float inv = 1.f / fmaxf(dsum, 1e-9f);
  float av = sel4(a0, a1, a2, a3, g);  // dim g*16+q == lane
  x2b[(size_t)wid * 64 + lane] = f2b(fmaxf(av * inv + b2[lane], 0.f));
}

// ---------------- pooling + classifier head (deterministic, no atomics) ----------------
__global__ __launch_bounds__(1024) void k_pool(const unsigned short* __restrict__ x2b,
                                               const int* __restrict__ gid,
                                               const float* __restrict__ Wc,
                                               const float* __restrict__ bc,
                                               float* __restrict__ out) {
  int g = blockIdx.x;
  int t = threadIdx.x;
  int lo = 0, hi = NN;
  while (lo < hi) { int mid = (lo + hi) >> 1; if (gid[mid] < g) lo = mid + 1; else hi = mid; }
  int lb = lo;
  hi = NN;
  while (lo < hi) { int mid = (lo + hi) >> 1; if (gid[mid] < g + 1) lo = mid + 1; else hi = mid; }
  int le = lo;
  int d = t & 63, slice = t >> 6;  // 16 node-slices x 64 dims
  float s = 0.f;
  for (int n = lb + slice; n < le; n += 16) s += b2f(x2b[(size_t)n * 64 + d]);
  __shared__ float ws[16][64];
  ws[slice][d] = s;
  __syncthreads();
  if (t < 64) {
    float p = 0.f;
#pragma unroll
    for (int i = 0; i < 16; i++) p += ws[i][d];
    p /= fmaxf((float)(le - lb), 1.f);
    float a0 = p * Wc[d * 2 + 0];
    float a1 = p * Wc[d * 2 + 1];
#pragma unroll
    for (int off = 32; off; off >>= 1) { a0 += __shfl_xor(a0, off); a1 += __shfl_xor(a1, off); }
    if (d == 0) { out[g * 2 + 0] = a0 + bc[0]; out[g * 2 + 1] = a1 + bc[1]; }
  }
}

extern "C" void kernel_launch(void* const* d_in, const int* in_sizes, int n_in,
                              void* d_out, int out_size, void* d_ws, size_t ws_size,
                              hipStream_t stream) {
  const float* h = (const float*)d_in[0];
  const int* src = (const int*)d_in[1];
  const int* dst = (const int*)d_in[2];
  const int* gid = (const int*)d_in[3];
  const float* W1 = (const float*)d_in[4];
  const float* al1 = (const float*)d_in[5];
  const float* ar1 = (const float*)d_in[6];
  const float* b1 = (const float*)d_in[7];
  const float* W2 = (const float*)d_in[8];
  const float* al2 = (const float*)d_in[9];
  const float* ar2 = (const float*)d_in[10];
  const float* b2 = (const float*)d_in[11];
  const float* Wc = (const float*)d_in[12];
  const float* bc = (const float*)d_in[13];
  float* out = (float*)d_out;

  char* wsp = (char*)d_ws;
  size_t off = 0;
  auto take = [&](size_t bytes) -> void* {
    void* p = wsp + off;
    off = (off + bytes + 255) & ~(size_t)255;
    return p;
  };
  unsigned int* feat1f8 = (unsigned int*)take((size_t)NN * 256);          // 12.8 MB
  unsigned short* x1b = (unsigned short*)take((size_t)NN * 256 * 2);      // 25.6 MB
  unsigned int* feat2f8 = (unsigned int*)take((size_t)NN * 64);           // 3.2 MB
  unsigned short* x2b = (unsigned short*)take((size_t)NN * 64 * 2);       // 6.4 MB
  unsigned short* w1t_hi = (unsigned short*)take((size_t)256 * IND * 2);  // 64 KB
  unsigned short* w2t_pre = (unsigned short*)take((size_t)64 * 256 * 2);  // 32 KB
  float4* el1 = (float4*)take((size_t)NN * 16);
  float4* er1 = (float4*)take((size_t)NN * 16);
  float* el2 = (float*)take((size_t)NN * 4);
  float* er2 = (float*)take((size_t)NN * 4);
  int* counts = (int*)take((size_t)NN * 4);
  int* offs = (int*)take((size_t)(NN + 1) * 4);
  int2* sd = (int2*)take((size_t)NE * 8);            // 6.4 MB
  int2* ebuf = (int2*)take((size_t)NE * 8);          // 6.4 MB
  int4* erec1 = (int4*)take((size_t)NE * 16);        // 12.8 MB
  int* bsums = (int*)take((size_t)NSB * 4);
  int* boffs = (int*)take((size_t)NSB * 4);
  int* bcursor = (int*)take((size_t)NBUCK * 4);

  // zero counts with our own parallel kernel
  k_zero<<<NSB, 1024, 0, stream>>>(counts);

  // prep (W1 transpose + W2 swizzle + edge count)
  k_prep<<<(NE + 255) / 256, 256, 0, stream>>>(W1, W2, dst, w1t_hi, w2t_pre, counts);

  // hierarchical scan + two-pass partition scatter
  k_scanA<<<NSB, 1024, 0, stream>>>(counts, bsums);
  k_scanB<<<1, 64, 0, stream>>>(bsums, boffs, bcursor);
  k_scanC<<<NSB, 1024, 0, stream>>>(counts, boffs, offs);
  k_part<<<NPBLK, 256, 0, stream>>>(src, dst, offs, bcursor, ebuf);
  k_scat2<<<NBUCK, 256, 0, stream>>>(ebuf, offs, sd);

  // layer 1
  k_gemm1<<<(NN + 63) / 64, 256, 0, stream>>>(h, w1t_hi, al1, ar1, feat1f8, el1, er1);
  k_edge1<<<(NE + 255) / 256, 256, 0, stream>>>(sd, el1, er1, erec1);
  k_agg1<<<(NN * 64 + 255) / 256, 256, 0, stream>>>(offs, erec1, feat1f8, b1, x1b);

  // layer 2 (edge weights fused into agg2)
  k_gemm2<<<(NN + 63) / 64, 256, 0, stream>>>(x1b, w2t_pre, al2, ar2, feat2f8, el2, er2);
  k_agg2<<<(NN * 64 + 255) / 256, 256, 0, stream>>>(offs, sd, el2, er2, feat2f8, b2, x2b);

  // pool + head (fused, atomic-free)
  k_pool<<<NG, 1024, 0, stream>>>(x2b, gid, Wc, bc, out);
}